// Round 5
// baseline (27.670 us; speedup 1.0000x reference)
//
#include <hip/hip_runtime.h>
#include <math.h>
#include <utility>

#define DIMS  16
#define BATCH 32768
#define NPAIR 136
#define NB    128      // samples per block
#define NMT   5        // M-tiles of 32 (rows 0..159)
#define NNT   4        // N-tiles of 32 (128 samples)
#define NKK   10       // K-steps of 16 (K = 160)

typedef short s16x8  __attribute__((ext_vector_type(8)));
typedef float f32x16 __attribute__((ext_vector_type(16)));

#define A_ELEMS (NKK*NMT*64*8)       // 25600 bf16
#define P_ELEMS (NKK*NNT*64*8)       // 20480 bf16
#define A_BYTES (A_ELEMS*2)          // 51200
#define P_BYTES (P_ELEMS*2)          // 40960
#define RED_OFF (A_BYTES+P_BYTES)
#define LDS_BYTES (RED_OFF + NMT*NNT*32*4)   // + 2560 = 94720 B (< 160K, 1 block/CU)

// ---------- compile-time combinatorics (lex = combinations_with_replacement) ----------
constexpr int pairlex(int i0, int i1){ int s=0; for(int j=0;j<i0;++j) s+=(DIMS-j); return s+(i1-i0); }
constexpr int pid_i0(int pid){ int i0=0,rem=pid; while(rem>=DIMS-i0){rem-=DIMS-i0;++i0;} return i0; }
constexpr int pid_i1(int pid){ int i0=0,rem=pid; while(rem>=DIMS-i0){rem-=DIMS-i0;++i0;} return i0+rem; }
constexpr int cnt3(int j){ return (DIMS-j)*(DIMS+1-j)/2; }
constexpr int off3(int i0){ int s=0; for(int j=0;j<i0;++j) s+=cnt3(j); return s; }
constexpr int cnt4j(int j){ return (DIMS-j)*(DIMS+1-j)*(DIMS+2-j)/6; }
constexpr int off4(int i0){ int s=0; for(int j=0;j<i0;++j) s+=cnt4j(j); return s; }
// W layout: [0]=const, [1..16]=deg1, [17..152]=deg2, [153..968]=deg3, [969..4844]=deg4
constexpr int w3rowbase(int i0){ return 1+DIMS+NPAIR+off3(i0); }
constexpr int w4base(int i0,int i1){ int s=off4(i0); for(int b=i0;b<i1;++b) s+=cnt3(b); return 1+DIMS+NPAIR+816+s; }
static_assert(pairlex(15,15)==135 && off3(DIMS)==816 && off4(DIMS)==3876, "combi");
static_assert(w3rowbase(15)==968-15 || true, "");
static_assert(w4base(15,15)==4844, "wtail");

// ---------- row metadata (verified by r3 pass): A[row][k] = gate*W[wb+k-qs] for qs<=k<qe ----------
struct RowMeta { short qs, qe, wb, deg; };
struct RowTab  { RowMeta m[NMT*32]; };
constexpr RowTab make_rowtab(){
    RowTab t{};
    for (int r = 0; r < NMT*32; ++r) {
        RowMeta rm{0,0,0,0};
        if (r < NPAIR) {                       // S4 rows: cols = pairs (i2,i3) >= (i1,i1)
            int i0 = pid_i0(r), i1 = pid_i1(r);
            rm = RowMeta{ (short)pairlex(i1,i1), (short)NPAIR, (short)w4base(i0,i1), 4 };
        } else if (r < NPAIR + DIMS) {         // S3 rows: cols = pairs (i1,i2) >= (i0,i0)
            int i0 = r - NPAIR;
            rm = RowMeta{ (short)pairlex(i0,i0), (short)NPAIR, (short)w3rowbase(i0), 3 };
        } else if (r == 152) {                 // S2: dot(W2, pairs)
            rm = RowMeta{ 0, (short)NPAIR, (short)(1+DIMS), 2 };
        } else if (r == 153) {                 // S1: dot(W1, x) (F cols 136..151 = x)
            rm = RowMeta{ (short)NPAIR, (short)(NPAIR+DIMS), 1, 1 };
        }
        t.m[r] = rm;
    }
    return t;
}

// ---------- DESC: A-slot (fragment layout) -> (deg<<13 | W index); 0 => zero slot ----------
struct DescT { unsigned short d[A_ELEMS]; };
constexpr DescT make_desc(){
    DescT D{};
    const RowTab rt = make_rowtab();
    for (int id = 0; id < A_ELEMS; ++id) {
        const int e = id & 7, ln = (id >> 3) & 63, mtkk = id >> 9;
        const int mt = mtkk % NMT, kk = mtkk / NMT;
        const int row = mt*32 + (ln & 31);
        const int k   = kk*16 + 4*(ln >> 5) + (e & 3) + 8*(e >> 2);
        const RowMeta rm = rt.m[row];
        unsigned short v = 0;
        if (k >= rm.qs && k < rm.qe)
            v = (unsigned short)(((unsigned)rm.deg << 13) | (unsigned)(rm.wb + k - rm.qs));
        D.d[id] = v;
    }
    return D;
}
__device__ __constant__ DescT DESC = make_desc();

// ---------- bf16 helpers ----------
__device__ __forceinline__ ushort f2bf(float f){
    union { float f; unsigned u; } v{f};
    return (ushort)((v.u + 0x7FFF + ((v.u >> 16) & 1)) >> 16);   // RNE
}
__device__ __forceinline__ float bf2f(short h){
    union { unsigned u; float f; } v{ (unsigned)(ushort)h << 16 };
    return v.f;
}

// ---------- static_for ----------
template<typename F, int... Is>
__device__ __forceinline__ void sfor_impl(F&& f, std::integer_sequence<int,Is...>){
    (f(std::integral_constant<int,Is>{}), ...);
}
template<int N, typename F>
__device__ __forceinline__ void sfor(F&& f){
    sfor_impl(static_cast<F&&>(f), std::make_integer_sequence<int,N>{});
}

// F row value (static row index -> static xv indices)
template<int R>
__device__ __forceinline__ float fval(const float (&xv)[DIMS]){
    if constexpr      (R < NPAIR)        return xv[pid_i0(R)] * xv[pid_i1(R)];
    else if constexpr (R < NPAIR+DIMS)   return xv[R - NPAIR];
    else if constexpr (R < 154)          return 1.0f;
    else                                 return 0.0f;
}

// pack 8 rows of F for (frag kk, half h) into one b128 LDS write.
// B-frag: lane l -> n=l&31, k_inner = 4*(l>>5)+(e&3)+8*(e>>2)  (r3-verified)
template<int KK, int H>
__device__ __forceinline__ void emitF(ushort* __restrict__ P_sh, int s, const float (&xv)[DIMS]){
    s16x8 v;
    sfor<8>([&](auto E){ constexpr int e = decltype(E)::value;
        constexpr int row = 16*KK + 4*H + (e & 3) + 8*(e >> 2);
        v[e] = (short)f2bf(fval<row>(xv)); });
    const int nt = s >> 5, l = (s & 31) + 32*H;
    *reinterpret_cast<s16x8*>(P_sh + (size_t)((KK*NNT + nt)*64 + l)*8) = v;
}

template<int G>
__device__ __forceinline__ void buildF(ushort* __restrict__ P_sh, int s, const float (&xv)[DIMS]){
    emitF<2*G,   0>(P_sh, s, xv);
    emitF<2*G,   1>(P_sh, s, xv);
    emitF<2*G+1, 0>(P_sh, s, xv);
    emitF<2*G+1, 1>(P_sh, s, xv);
}

// Grid 256 x 640 threads (10 waves). LDS: A(50K) + F(40K) + red(2.5K).
__global__ __launch_bounds__(640, 1)
void poly_logreg_mfma2(const float* __restrict__ x, const float* __restrict__ W,
                       const float* __restrict__ b, const float* __restrict__ M_raw,
                       float* __restrict__ out)
{
    extern __shared__ char smem[];
    ushort* A_sh = reinterpret_cast<ushort*>(smem);
    ushort* P_sh = reinterpret_cast<ushort*>(smem + A_BYTES);
    float*  red  = reinterpret_cast<float*>(smem + RED_OFF);

    const int t = threadIdx.x, lane = t & 63, wv = t >> 6;
    const int s = t & (NB - 1);                 // sample 0..127
    const int g = t >> 7;                       // frag-group 0..4 (wave-uniform)

    // ---- issue x loads first (latency hidden under A-build) ----
    const float4* xp = reinterpret_cast<const float4*>(
        x + ((size_t)blockIdx.x * NB + s) * DIMS);
    const float4 xa = xp[0], xb = xp[1], xc = xp[2], xd = xp[3];

    // ---- degree gates (uniform) ----
    const float M  = 3.0f/(1.0f+__expf(-M_raw[0])) + 1.0f;
    const float g1 = 1.0f/(1.0f+__expf(-10.0f*(M-0.5f)));
    const float g2 = 1.0f/(1.0f+__expf(-10.0f*(M-1.5f)));
    const float g3 = 1.0f/(1.0f+__expf(-10.0f*(M-2.5f)));
    const float g4 = 1.0f/(1.0f+__expf(-10.0f*(M-3.5f)));

    // ---- A-build: coalesced DESC read, pipelined W gather, contiguous u16 store ----
    #pragma unroll 4
    for (int i = t; i < A_ELEMS; i += 640) {
        const unsigned short d = DESC.d[i];
        const int deg = d >> 13, src = d & 0x1FFF;
        const float gv = deg==4 ? g4 : deg==3 ? g3 : deg==2 ? g2 : deg==1 ? g1 : 0.0f;
        A_sh[i] = f2bf(gv * W[src]);
    }

    // ---- F-build: this thread owns rows [32g,32g+32) of sample s, 4x ds_write_b128 ----
    float xv[DIMS];
    xv[0]=xa.x; xv[1]=xa.y; xv[2]=xa.z; xv[3]=xa.w;
    xv[4]=xb.x; xv[5]=xb.y; xv[6]=xb.z; xv[7]=xb.w;
    xv[8]=xc.x; xv[9]=xc.y; xv[10]=xc.z; xv[11]=xc.w;
    xv[12]=xd.x; xv[13]=xd.y; xv[14]=xd.z; xv[15]=xd.w;
    switch (g) {
        case 0:  buildF<0>(P_sh, s, xv); break;
        case 1:  buildF<1>(P_sh, s, xv); break;
        case 2:  buildF<2>(P_sh, s, xv); break;
        case 3:  buildF<3>(P_sh, s, xv); break;
        default: buildF<4>(P_sh, s, xv); break;
    }
    __syncthreads();

    // ---- GEMM: wave wv -> mt = wv>>1, two N-tiles nt = 2*(wv&1)+tt ----
    {
        const int mt = wv >> 1, np = wv & 1;
        s16x8 af[NKK];
        sfor<NKK>([&](auto K){ constexpr int kk = decltype(K)::value;
            af[kk] = *reinterpret_cast<const s16x8*>(
                A_sh + (size_t)((kk*NMT + mt)*64 + lane)*8); });

        #pragma unroll
        for (int tt = 0; tt < 2; ++tt) {
            const int nt = 2*np + tt;
            f32x16 acc = {};
            s16x8 bk0 = {}, bk1 = {};
            sfor<NKK>([&](auto K){ constexpr int kk = decltype(K)::value;
                const s16x8 bf = *reinterpret_cast<const s16x8*>(
                    P_sh + (size_t)((kk*NNT + nt)*64 + lane)*8);
                if (kk == 2*mt)     bk0 = bf;       // wave-uniform cond, kept for epilogue
                if (kk == 2*mt + 1) bk1 = bf;
                acc = __builtin_amdgcn_mfma_f32_32x32x16_bf16(af[kk], bf, acc, 0, 0, 0); });

            // epilogue: logit partial = sum_r F[r]*S[r] over this tile's rows.
            // C/D: col=lane&31, row=(reg&3)+8*(reg>>2)+4*(lane>>5)  (r3-verified)
            float p = 0.f;
            sfor<16>([&](auto R){ constexpr int reg = decltype(R)::value;
                constexpr int rlo = reg & 3, rhi = reg >> 2;
                const s16x8 bsel = (rhi >> 1) ? bk1 : bk0;
                p = fmaf(bf2f(bsel[rlo + 4*(rhi & 1)]), acc[reg], p); });
            p += __shfl_xor(p, 32);                 // combine lane-halves (row halves)
            if (lane < 32) red[(mt*NNT + nt)*32 + lane] = p;
        }
    }
    __syncthreads();

    // ---- finalize 128 samples ----
    if (t < NB) {
        const int nt = t >> 5, c = t & 31;
        float logit = W[0] + b[0];
        #pragma unroll
        for (int mt = 0; mt < NMT; ++mt) logit += red[(mt*NNT + nt)*32 + c];
        out[(size_t)blockIdx.x * NB + t] = 1.0f/(1.0f+__expf(-logit));
    }
}

extern "C" void kernel_launch(void* const* d_in, const int* in_sizes, int n_in,
                              void* d_out, int out_size, void* d_ws, size_t ws_size,
                              hipStream_t stream)
{
    const float* x     = (const float*)d_in[0];
    const float* W     = (const float*)d_in[1];
    const float* b     = (const float*)d_in[2];
    const float* M_raw = (const float*)d_in[3];
    float* out = (float*)d_out;

    poly_logreg_mfma2<<<BATCH/NB, 640, LDS_BYTES, stream>>>(x, W, b, M_raw, out);
}